// Round 5
// baseline (73.757 us; speedup 1.0000x reference)
//
#include <hip/hip_runtime.h>
#include <hip/hip_bf16.h>
#include <math.h>

#define NB 4
#define NT 4096
#define NC 512
#define NH 64
#define KVBLK 64
#define LDK 72      // padded LDS row stride (bf16 elems) = 144 B
#define MASKV (-1e30f)

typedef __attribute__((ext_vector_type(8))) short bf16x8;
typedef __attribute__((ext_vector_type(4))) float f32x4;

__device__ inline unsigned short f2bf(float f) {
    __hip_bfloat16 h = __float2bfloat16(f);
    return *reinterpret_cast<unsigned short*>(&h);
}

// ---------------- Kernel 0: pack W^T bf16 [192][512], Wq pre-scaled ----------------
__global__ __launch_bounds__(256) void wconv(
    const float* __restrict__ Wk, const float* __restrict__ Wq,
    const float* __restrict__ Wv, unsigned short* __restrict__ Wt)
{
    int idx = blockIdx.x * 256 + threadIdx.x;   // 98304 = 512*192
    int n = idx % 192, c = idx / 192;
    int sel = n >> 6, h = n & 63;
    const float* W = (sel == 0) ? Wq : (sel == 1) ? Wk : Wv;
    float val = W[c * NH + h];
    if (sel == 0) val *= 0.044194173824159216f;  // 1/sqrt(512)
    Wt[n * NC + c] = f2bf(val);
}

// ---------------- Kernel 1: QKV projection as MFMA GEMM (BM=32) ----------------
// q,k written row-major [b*t][h]; v written TRANSPOSED vt[b][h][t] for the
// attention kernel's direct V^T fragment loads.
__global__ __launch_bounds__(256) void qkv_gemm(
    const float* __restrict__ x, const unsigned short* __restrict__ Wt,
    unsigned short* __restrict__ q, unsigned short* __restrict__ k,
    unsigned short* __restrict__ vt)
{
    __shared__ unsigned short xa[32][LDK];    // A tile  (4.6 KB)
    __shared__ unsigned short wb[192][LDK];   // B tile (27.6 KB)

    const int tid = threadIdx.x;
    const int w = tid >> 6, lane = tid & 63, l15 = lane & 15, g = lane >> 4;
    const size_t r0 = (size_t)blockIdx.x * 32;

    f32x4 acc[2][3];
    #pragma unroll
    for (int mt = 0; mt < 2; ++mt)
        #pragma unroll
        for (int nt = 0; nt < 3; ++nt) acc[mt][nt] = (f32x4){0.f,0.f,0.f,0.f};

    for (int c0 = 0; c0 < NC; c0 += 64) {
        __syncthreads();
        // stage A: 32x64 fp32 -> bf16 (one 8-chunk per thread)
        {
            int row = tid >> 3, f8 = tid & 7;
            const float* xp = x + (r0 + row) * NC + c0 + f8*8;
            float4 x0 = *reinterpret_cast<const float4*>(xp);
            float4 x1 = *reinterpret_cast<const float4*>(xp + 4);
            bf16x8 a8;
            a8[0]=f2bf(x0.x); a8[1]=f2bf(x0.y); a8[2]=f2bf(x0.z); a8[3]=f2bf(x0.w);
            a8[4]=f2bf(x1.x); a8[5]=f2bf(x1.y); a8[6]=f2bf(x1.z); a8[7]=f2bf(x1.w);
            *reinterpret_cast<bf16x8*>(&xa[row][f8*8]) = a8;
        }
        // stage B: 192x64 bf16
        #pragma unroll
        for (int i = 0; i < 6; ++i) {
            int idx = tid + 256*i;
            int row = idx >> 3, f8 = idx & 7;
            bf16x8 w8 = *reinterpret_cast<const bf16x8*>(Wt + (size_t)row * NC + c0 + f8*8);
            *reinterpret_cast<bf16x8*>(&wb[row][f8*8]) = w8;
        }
        __syncthreads();

        #pragma unroll
        for (int kk = 0; kk < 2; ++kk) {
            bf16x8 a[2], bfr[3];
            #pragma unroll
            for (int mt = 0; mt < 2; ++mt)
                a[mt] = *reinterpret_cast<const bf16x8*>(&xa[16*mt + l15][32*kk + 8*g]);
            #pragma unroll
            for (int nt = 0; nt < 3; ++nt)
                bfr[nt] = *reinterpret_cast<const bf16x8*>(&wb[48*w + 16*nt + l15][32*kk + 8*g]);
            __builtin_amdgcn_s_setprio(1);
            #pragma unroll
            for (int mt = 0; mt < 2; ++mt)
                #pragma unroll
                for (int nt = 0; nt < 3; ++nt)
                    acc[mt][nt] = __builtin_amdgcn_mfma_f32_16x16x32_bf16(a[mt], bfr[nt], acc[mt][nt], 0, 0, 0);
            __builtin_amdgcn_s_setprio(0);
        }
    }

    #pragma unroll
    for (int mt = 0; mt < 2; ++mt)
        #pragma unroll
        for (int nt = 0; nt < 3; ++nt) {
            int ncol = 48*w + 16*nt + l15;
            int sel = ncol >> 6, h = ncol & 63;
            if (sel < 2) {
                unsigned short* dst = (sel == 0) ? q : k;
                #pragma unroll
                for (int r = 0; r < 4; ++r)
                    dst[(r0 + 16*mt + 4*g + r) * NH + h] = f2bf(acc[mt][nt][r]);
            } else {
                // transposed store vt[b][h][t]: 4 consecutive t -> one 8B write
                int bb = (int)(r0 >> 12);                 // r0 / NT
                int trow = ((int)r0 & (NT-1)) + 16*mt + 4*g;
                unsigned int lo = (unsigned int)f2bf(acc[mt][nt][0]) | ((unsigned int)f2bf(acc[mt][nt][1]) << 16);
                unsigned int hi = (unsigned int)f2bf(acc[mt][nt][2]) | ((unsigned int)f2bf(acc[mt][nt][3]) << 16);
                *reinterpret_cast<uint2*>(&vt[((size_t)bb*NH + h)*NT + trow]) = make_uint2(lo, hi);
            }
        }
}

// ---------------- Kernel 2: barrier-free split-KV MFMA flash attention ----------------
// ONE WAVE per (32 q-rows, 512-kv chunk, batch). K and V^T fragments loaded
// directly global->register (L2-hot); swapped S^T = K·Q^T keeps softmax
// per-q-column in-register (reduce over g-groups = 2 shfls); P^T via a tiny
// per-wave LDS roundtrip. No __syncthreads anywhere.
__global__ __launch_bounds__(64, 3) void attn_part(
    const unsigned short* __restrict__ qg,
    const unsigned short* __restrict__ kg,
    const unsigned short* __restrict__ vtg,
    float* __restrict__ out,
    float* __restrict__ O_part,
    float* __restrict__ ML_part)
{
    const int qt = 127 - blockIdx.x;          // 32-row q-tile, heavy first
    const int nT = (qt >> 1) + 1;             // kv tiles of 64 needed
    const int ch = blockIdx.y;
    if (8 * ch >= nT) return;
    const int b  = blockIdx.z;

    __shared__ unsigned short p_lds[32][LDK];  // per-wave P^T roundtrip (4.6 KB)

    const int lane = threadIdx.x & 63;
    const int l15  = lane & 15;
    const int g    = lane >> 4;

    const int q0 = qt * 32;
    const size_t base = (size_t)b * NT * NH;

    // Q fragments (B-operand): qf[qc][kk] = Q[q0+16qc+l15][8g+32kk .. +8)
    bf16x8 qf[2][2];
    #pragma unroll
    for (int qc = 0; qc < 2; ++qc) {
        const unsigned short* qp = qg + base + (size_t)(q0 + 16*qc + l15) * NH + 8*g;
        qf[qc][0] = *reinterpret_cast<const bf16x8*>(qp);
        qf[qc][1] = *reinterpret_cast<const bf16x8*>(qp + 32);
    }

    f32x4 ot[4][2];   // O^T: lane holds O^T[16dt+4g+r][q0+16qc+l15]
    #pragma unroll
    for (int dt = 0; dt < 4; ++dt)
        #pragma unroll
        for (int qc = 0; qc < 2; ++qc) ot[dt][qc] = (f32x4){0.f,0.f,0.f,0.f};
    float m0 = MASKV, m1 = MASKV, l0 = 0.f, l1 = 0.f;

    const int tBeg = 8 * ch;
    const int tEnd = min(8 * (ch + 1), nT);

    for (int it = tBeg; it < tEnd; ++it) {
        const int s0 = it * KVBLK;

        // ---- K fragments direct from global (8 x b128, 16 rows x 16B gather) ----
        const unsigned short* kbase = kg + base + (size_t)(s0 + l15) * NH + 8*g;
        bf16x8 ka[4][2];
        #pragma unroll
        for (int t = 0; t < 4; ++t)
            #pragma unroll
            for (int kk = 0; kk < 2; ++kk)
                ka[t][kk] = *reinterpret_cast<const bf16x8*>(kbase + t*16*NH + kk*32);

        // ---- S^T = K · Q^T (16 MFMA) ----
        f32x4 s[4][2];
        __builtin_amdgcn_s_setprio(1);
        #pragma unroll
        for (int t = 0; t < 4; ++t)
            #pragma unroll
            for (int qc = 0; qc < 2; ++qc) {
                s[t][qc] = __builtin_amdgcn_mfma_f32_16x16x32_bf16(ka[t][0], qf[qc][0], (f32x4){0.f,0.f,0.f,0.f}, 0, 0, 0);
                s[t][qc] = __builtin_amdgcn_mfma_f32_16x16x32_bf16(ka[t][1], qf[qc][1], s[t][qc], 0, 0, 0);
            }
        __builtin_amdgcn_s_setprio(0);

        // ---- V^T fragments direct from global; in flight under softmax ----
        const unsigned short* vbase = vtg + ((size_t)b*NH + l15)*NT + s0 + 8*g;
        bf16x8 vf[4][2];
        #pragma unroll
        for (int dt = 0; dt < 4; ++dt)
            #pragma unroll
            for (int kk = 0; kk < 2; ++kk)
                vf[dt][kk] = *reinterpret_cast<const bf16x8*>(vbase + (size_t)dt*16*NT + kk*32);

        // ---- causal mask (diagonal-touching tiles only; wave-uniform test) ----
        if (s0 + KVBLK - 1 > q0) {
            #pragma unroll
            for (int t = 0; t < 4; ++t)
                #pragma unroll
                for (int qc = 0; qc < 2; ++qc) {
                    const int qr = q0 + 16*qc + l15;
                    #pragma unroll
                    for (int r = 0; r < 4; ++r)
                        if (s0 + 16*t + 4*g + r > qr) s[t][qc][r] = MASKV;
                }
        }

        // ---- online softmax per q-column ----
        float pm0 = MASKV, pm1 = MASKV;
        #pragma unroll
        for (int t = 0; t < 4; ++t)
            #pragma unroll
            for (int r = 0; r < 4; ++r) {
                pm0 = fmaxf(pm0, s[t][0][r]);
                pm1 = fmaxf(pm1, s[t][1][r]);
            }
        pm0 = fmaxf(pm0, __shfl_xor(pm0, 16)); pm0 = fmaxf(pm0, __shfl_xor(pm0, 32));
        pm1 = fmaxf(pm1, __shfl_xor(pm1, 16)); pm1 = fmaxf(pm1, __shfl_xor(pm1, 32));

        // defer-max (T13): rescale only when max grew by > 8
        if (!__all(pm0 <= m0 + 8.f && pm1 <= m1 + 8.f)) {
            float mn0 = fmaxf(m0, pm0), mn1 = fmaxf(m1, pm1);
            float c0 = __expf(m0 - mn0), c1 = __expf(m1 - mn1);
            l0 *= c0; l1 *= c1;
            #pragma unroll
            for (int dt = 0; dt < 4; ++dt)
                #pragma unroll
                for (int e = 0; e < 4; ++e) {
                    ot[dt][0][e] *= c0;
                    ot[dt][1][e] *= c1;
                }
            m0 = mn0; m1 = mn1;
        }

        float ps0 = 0.f, ps1 = 0.f;
        #pragma unroll
        for (int t = 0; t < 4; ++t)
            #pragma unroll
            for (int r = 0; r < 4; ++r) {
                float p0 = __expf(s[t][0][r] - m0);
                float p1 = __expf(s[t][1][r] - m1);
                s[t][0][r] = p0; s[t][1][r] = p1;
                ps0 += p0; ps1 += p1;
            }

        // P^T -> per-wave LDS as P[q][kv] (u32-packed pairs)
        #pragma unroll
        for (int qc = 0; qc < 2; ++qc)
            #pragma unroll
            for (int t = 0; t < 4; ++t) {
                unsigned int w0 = (unsigned int)f2bf(s[t][qc][0]) | ((unsigned int)f2bf(s[t][qc][1]) << 16);
                unsigned int w1 = (unsigned int)f2bf(s[t][qc][2]) | ((unsigned int)f2bf(s[t][qc][3]) << 16);
                *reinterpret_cast<unsigned int*>(&p_lds[16*qc + l15][16*t + 4*g])     = w0;
                *reinterpret_cast<unsigned int*>(&p_lds[16*qc + l15][16*t + 4*g + 2]) = w1;
            }

        ps0 += __shfl_xor(ps0, 16); ps0 += __shfl_xor(ps0, 32);
        ps1 += __shfl_xor(ps1, 16); ps1 += __shfl_xor(ps1, 32);
        l0 += ps0; l1 += ps1;

        // ---- O^T += V^T · P^T (16 MFMA) ----
        bf16x8 pf[2][2];
        #pragma unroll
        for (int qc = 0; qc < 2; ++qc)
            #pragma unroll
            for (int kk = 0; kk < 2; ++kk)
                pf[qc][kk] = *reinterpret_cast<const bf16x8*>(&p_lds[16*qc + l15][8*g + 32*kk]);
        __builtin_amdgcn_s_setprio(1);
        #pragma unroll
        for (int kk = 0; kk < 2; ++kk)
            #pragma unroll
            for (int dt = 0; dt < 4; ++dt)
                #pragma unroll
                for (int qc = 0; qc < 2; ++qc)
                    ot[dt][qc] = __builtin_amdgcn_mfma_f32_16x16x32_bf16(vf[dt][kk], pf[qc][kk], ot[dt][qc], 0, 0, 0);
        __builtin_amdgcn_s_setprio(0);
    }

    if (nT <= 8) {
        // single chunk: final output
        const float inv0 = 1.f / l0, inv1 = 1.f / l1;
        #pragma unroll
        for (int qc = 0; qc < 2; ++qc) {
            float inv = qc ? inv1 : inv0;
            float* orow = out + base + (size_t)(q0 + 16*qc + l15) * NH;
            #pragma unroll
            for (int dt = 0; dt < 4; ++dt) {
                f32x4 o4;
                #pragma unroll
                for (int r = 0; r < 4; ++r) o4[r] = ot[dt][qc][r] * inv;
                *reinterpret_cast<f32x4*>(&orow[16*dt + 4*g]) = o4;
            }
        }
    } else {
        const int slot = ((b * 128 + qt) << 3) + ch;
        float* op = O_part + (size_t)slot * (32*NH);
        #pragma unroll
        for (int qc = 0; qc < 2; ++qc)
            #pragma unroll
            for (int dt = 0; dt < 4; ++dt)
                *reinterpret_cast<f32x4*>(&op[(size_t)(16*qc + l15) * NH + 16*dt + 4*g]) = ot[dt][qc];
        if (g == 0) {
            float* mlp = ML_part + (size_t)slot * 64;
            *reinterpret_cast<float2*>(&mlp[2*l15])        = make_float2(m0, l0);
            *reinterpret_cast<float2*>(&mlp[2*(16 + l15)]) = make_float2(m1, l1);
        }
    }
}

// ---------------- Kernel 3: merge split-KV partials (qt >= 16) ----------------
__global__ __launch_bounds__(256) void attn_merge(
    const float* __restrict__ O_part,
    const float* __restrict__ ML_part,
    float* __restrict__ out)
{
    const int qt = 16 + blockIdx.x;
    const int b  = blockIdx.y;
    const int nch = (((qt >> 1) + 1) + 7) >> 3;
    const int slot0 = ((b * 128 + qt) << 3);
    const int row = threadIdx.x >> 3;          // 0..31
    const int dq  = (threadIdx.x & 7) * 8;     // 8 d's per thread

    float M = MASKV;
    for (int c = 0; c < nch; ++c)
        M = fmaxf(M, ML_part[(size_t)(slot0 + c) * 64 + 2*row]);

    float L = 0.f;
    float acc[8];
    #pragma unroll
    for (int j = 0; j < 8; ++j) acc[j] = 0.f;

    for (int c = 0; c < nch; ++c) {
        const float* mlp = &ML_part[(size_t)(slot0 + c) * 64 + 2*row];
        float wgt = __expf(mlp[0] - M);
        L += wgt * mlp[1];
        const float* op = O_part + (size_t)(slot0 + c) * (32*NH) + (size_t)row * NH + dq;
        #pragma unroll
        for (int j4 = 0; j4 < 2; ++j4) {
            float4 o4 = *reinterpret_cast<const float4*>(op + 4*j4);
            acc[4*j4+0] = fmaf(wgt, o4.x, acc[4*j4+0]);
            acc[4*j4+1] = fmaf(wgt, o4.y, acc[4*j4+1]);
            acc[4*j4+2] = fmaf(wgt, o4.z, acc[4*j4+2]);
            acc[4*j4+3] = fmaf(wgt, o4.w, acc[4*j4+3]);
        }
    }

    const float inv = 1.f / L;
    float* orow = out + (size_t)b * NT * NH + (size_t)(qt * 32 + row) * NH + dq;
    #pragma unroll
    for (int j4 = 0; j4 < 2; ++j4) {
        float4 o4;
        o4.x = acc[4*j4+0] * inv;
        o4.y = acc[4*j4+1] * inv;
        o4.z = acc[4*j4+2] * inv;
        o4.w = acc[4*j4+3] * inv;
        *reinterpret_cast<float4*>(orow + 4*j4) = o4;
    }
}

extern "C" void kernel_launch(void* const* d_in, const int* in_sizes, int n_in,
                              void* d_out, int out_size, void* d_ws, size_t ws_size,
                              hipStream_t stream) {
    const float* x  = (const float*)d_in[0];
    const float* Wk = (const float*)d_in[1];
    const float* Wq = (const float*)d_in[2];
    const float* Wv = (const float*)d_in[3];
    float* out = (float*)d_out;

    const size_t n = (size_t)NB * NT * NH;            // 1,048,576
    unsigned short* qb = (unsigned short*)d_ws;       // 2 MB
    unsigned short* kb = qb + n;                      // 2 MB
    unsigned short* vt = kb + n;                      // 2 MB (transposed [b][h][t])
    unsigned short* Wt = vt + n;                      // 196 KB
    float* O_part  = (float*)(Wt + 192 * NC);         // 4096 slots * 8 KB = 33.5 MB
    float* ML_part = O_part + (size_t)4096 * 32 * NH; // 4096 * 256 B = 1 MB

    wconv<<<(192*NC)/256, 256, 0, stream>>>(Wk, Wq, Wv, Wt);
    qkv_gemm<<<(NB*NT)/32, 256, 0, stream>>>(x, Wt, qb, kb, vt);

    dim3 pgrid(128, 8, NB);
    attn_part<<<pgrid, 64, 0, stream>>>(qb, kb, vt, out, O_part, ML_part);
    dim3 mgrid(112, NB);
    attn_merge<<<mgrid, 256, 0, stream>>>(O_part, ML_part, out);
}